// Round 4
// baseline (39.092 us; speedup 1.0000x reference)
//
#include <hip/hip_runtime.h>
#include <hip/hip_bf16.h>

#define F_FIELDS 39
#define VOCAB    100000
#define EMB      16
#define BATCH    16384
#define H1       32
#define H2       32
#define KSTEPS   20   /* K = 640 = 20 x 32 */
#define KPW      5    /* MFMA k-steps per wave (4-way split) */
#define GPW      10   /* gather fields per wave (4 waves x 10 = 40 >= 39) */

typedef __bf16 bf16x8 __attribute__((ext_vector_type(8)));
typedef __bf16 bf16x4 __attribute__((ext_vector_type(4)));
typedef float  f32x4  __attribute__((ext_vector_type(4)));   // clang ext-vector (nontemporal-load friendly)

// ---------------- pre-kernel: W1 (f32, [624][32]) -> bf16 MFMA-B fragments in d_ws ----------------
// frag id = (kstep*2 + nhalf)*64 + lane; element j: k = kstep*32 + (lane>>4)*8 + j, n = nhalf*16 + (lane&15)
__global__ __launch_bounds__(256) void swizzle_w1_kernel(const float* __restrict__ W1,
                                                         __bf16* __restrict__ ws)
{
    int fidx = blockIdx.x * 256 + threadIdx.x;
    if (fidx >= KSTEPS * 2 * 64) return;
    int lane = fidx & 63;
    int nh   = (fidx >> 6) & 1;
    int ks   = fidx >> 7;
    int k0   = ks * 32 + (lane >> 4) * 8;
    int n    = nh * 16 + (lane & 15);
    __bf16 vals[8];
    #pragma unroll
    for (int j = 0; j < 8; ++j) {
        int k = k0 + j;
        vals[j] = (k < F_FIELDS * EMB) ? (__bf16)W1[k * H1 + n] : (__bf16)0.0f;
    }
    *reinterpret_cast<bf16x8*>(&ws[fidx * 8]) = *reinterpret_cast<const bf16x8*>(vals);
}

// ---------------- main kernel ----------------
// Block = 256 threads = 4 waves = 16 samples.
// Gather phase: lane (s = l&15, q = l>>4) loads QUARTER q (16B) of row (sample s, field f),
//   f = h + 4*i (i = 0..9) -> one instruction = 16 rows, 4 lanes coalesce per 64B row.
//   FM stats accumulated in f32 per lane (positions q*4..q*4+3); scaled row -> eds (bf16).
// MFMA phase: wave h does ksteps ks = h+4j; A-frag lane (s,qa): field 2ks+(qa>>1),
//   positions (qa&1)*8..+7  ->  one ds_read_b128 from eds[f][s][p0].
__global__ __launch_bounds__(256, 4) void deepfm_main(
    const int*   __restrict__ Xi,  const float* __restrict__ Xv,
    const float* __restrict__ emb1,const float* __restrict__ emb2,
    const __bf16* __restrict__ wsW1,
    const float* __restrict__ b1,  const float* __restrict__ W2,
    const float* __restrict__ b2,  const float* __restrict__ bias,
    float* __restrict__ out)
{
    __shared__ int   sXi[16 * F_FIELDS];                 // 2.4 KB
    __shared__ float sXv[16 * F_FIELDS];                 // 2.4 KB
    __shared__ __align__(16) __bf16 eds[40][16][16];     // 20 KB  scaled rows (bf16), [field][sample][pos]
    __shared__ float pacc[4][16][32];                    // 8 KB   per-wave layer-1 partials
    __shared__ float sbuf[4][16][16];                    // 4 KB   per-wave FM s-vector partials
    __shared__ float qbuf[4][16];                        // per-wave FM sq-sum partials
    __shared__ float fbuf[4][16];                        // per-wave first-order partials
    __shared__ float W2s[H1 * H2];                       // 4 KB
    __shared__ float hs[16][32];                         // 2 KB   relu(layer-1)

    const int t    = threadIdx.x;
    const int h    = t >> 6;           // wave id
    const int l    = t & 63;
    const int s    = l & 15;           // sample within block
    const int q    = l >> 4;           // quarter / frag row-group
    const int blk  = blockIdx.x;

    // ---- coalesced stage of this block's Xi/Xv rows ----
    {
        const int base = blk * 16 * F_FIELDS;
        for (int i = t; i < 16 * F_FIELDS; i += 256) {
            sXi[i] = Xi[base + i];
            sXv[i] = Xv[base + i];
        }
    }
    reinterpret_cast<float4*>(W2s)[t] = reinterpret_cast<const float4*>(W2)[t];
    __syncthreads();

    // ---- issue all emb2 quarter-gathers (10 x 16B per lane, nontemporal) ----
    f32x4 g[GPW]; float xvg[GPW];
    #pragma unroll
    for (int i = 0; i < GPW; ++i) {
        int f  = h + 4 * i;                   // 0..39
        bool v = (f < F_FIELDS);
        int fi = v ? f : 0;
        int idx = sXi[s * F_FIELDS + fi];
        xvg[i]  = v ? sXv[s * F_FIELDS + fi] : 0.0f;
        const f32x4* rp = reinterpret_cast<const f32x4*>(emb2 + (fi * VOCAB + idx) * EMB) + q;
        g[i] = __builtin_nontemporal_load(rp);
    }
    // ---- issue emb1 gathers: fields f = 4h+q+16i ----
    float e1v[3], xvf[3];
    #pragma unroll
    for (int i = 0; i < 3; ++i) {
        int f  = 4 * h + q + 16 * i;
        bool v = (f < F_FIELDS);
        int fi = v ? f : 0;
        int idx = sXi[s * F_FIELDS + fi];
        xvf[i] = v ? sXv[s * F_FIELDS + fi] : 0.0f;
        e1v[i] = __builtin_nontemporal_load(emb1 + (fi * VOCAB + idx));
    }

    // ---- consume gathers: FM stats (f32) + scaled bf16 rows -> LDS ----
    float sa4[4] = {0.f, 0.f, 0.f, 0.f};
    float qq = 0.f;
    #pragma unroll
    for (int i = 0; i < GPW; ++i) {
        int f = h + 4 * i;
        float xv = xvg[i];
        float e0 = g[i][0] * xv, e1 = g[i][1] * xv, e2 = g[i][2] * xv, e3 = g[i][3] * xv;
        sa4[0] += e0; sa4[1] += e1; sa4[2] += e2; sa4[3] += e3;
        qq += e0*e0 + e1*e1 + e2*e2 + e3*e3;
        bf16x4 bv = { (__bf16)e0, (__bf16)e1, (__bf16)e2, (__bf16)e3 };
        *reinterpret_cast<bf16x4*>(&eds[f][s][q * 4]) = bv;   // f=39 pad row: zeros (xv=0)
    }

    // FM partials: s-vector quarter per lane; sq-sum reduced over quarters
    *reinterpret_cast<float4*>(&sbuf[h][s][q * 4]) = make_float4(sa4[0], sa4[1], sa4[2], sa4[3]);
    qq += __shfl_xor(qq, 16);
    qq += __shfl_xor(qq, 32);
    if (l < 16) qbuf[h][s] = qq;

    // first-order partial
    float facc = 0.f;
    #pragma unroll
    for (int i = 0; i < 3; ++i) facc += e1v[i] * xvf[i];
    facc += __shfl_xor(facc, 16);
    facc += __shfl_xor(facc, 32);
    if (l < 16) fbuf[h][s] = facc;

    __syncthreads();   // eds ready

    // ---- MFMA phase: wave h does ksteps ks = h + 4j ----
    const bf16x8* wsf = reinterpret_cast<const bf16x8*>(wsW1);
    f32x4 acc0 = {0.f,0.f,0.f,0.f}, acc1 = {0.f,0.f,0.f,0.f};
    #pragma unroll
    for (int j = 0; j < KPW; ++j) {
        int ks = h + 4 * j;                    // 0..19
        int f  = 2 * ks + (q >> 1);            // 0..39 (39 = zero pad row)
        int p0 = (q & 1) * 8;
        bf16x8 afr = *reinterpret_cast<const bf16x8*>(&eds[f][s][p0]);
        bf16x8 b0  = wsf[(ks * 2 + 0) * 64 + l];
        bf16x8 b1f = wsf[(ks * 2 + 1) * 64 + l];
        acc0 = __builtin_amdgcn_mfma_f32_16x16x32_bf16(afr, b0,  acc0, 0, 0, 0);
        acc1 = __builtin_amdgcn_mfma_f32_16x16x32_bf16(afr, b1f, acc1, 0, 0, 0);
    }

    // ---- layer-1 partials -> LDS (b1 folded into wave 0) ----
    float badd0 = (h == 0) ? b1[s]      : 0.f;
    float badd1 = (h == 0) ? b1[16 + s] : 0.f;
    #pragma unroll
    for (int r = 0; r < 4; ++r) {
        int row = q * 4 + r;                   // C-frag: row = q*4+r, col = lane&15
        pacc[h][row][s]      = acc0[r] + badd0;
        pacc[h][row][16 + s] = acc1[r] + badd1;
    }
    __syncthreads();

    // ---- h = relu(sum of partials) ----
    {
        int ss = t >> 4, c = t & 15;
        hs[ss][c]      = fmaxf(pacc[0][ss][c]      + pacc[1][ss][c]      + pacc[2][ss][c]      + pacc[3][ss][c],      0.f);
        hs[ss][c + 16] = fmaxf(pacc[0][ss][c + 16] + pacc[1][ss][c + 16] + pacc[2][ss][c + 16] + pacc[3][ss][c + 16], 0.f);
    }
    __syncthreads();

    // ---- final: 16 threads per sample ----
    const int so = t >> 4;
    const int u  = t & 15;

    float sv = sbuf[0][so][u] + sbuf[1][so][u] + sbuf[2][so][u] + sbuf[3][so][u];
    float s2 = sv * sv;

    float a0 = b2[2 * u], a1 = b2[2 * u + 1];
    #pragma unroll
    for (int i = 0; i < H1; ++i) {
        float hv = hs[so][i];
        a0 += hv * W2s[i * H2 + 2 * u];
        a1 += hv * W2s[i * H2 + 2 * u + 1];
    }
    float psum = fmaxf(a0, 0.f) + fmaxf(a1, 0.f);

    psum += __shfl_xor(psum, 1);  s2 += __shfl_xor(s2, 1);
    psum += __shfl_xor(psum, 2);  s2 += __shfl_xor(s2, 2);
    psum += __shfl_xor(psum, 4);  s2 += __shfl_xor(s2, 4);
    psum += __shfl_xor(psum, 8);  s2 += __shfl_xor(s2, 8);

    if (u == 0) {
        float qtot = qbuf[0][so] + qbuf[1][so] + qbuf[2][so] + qbuf[3][so];
        float ftot = fbuf[0][so] + fbuf[1][so] + fbuf[2][so] + fbuf[3][so];
        out[blk * 16 + so] = psum + 0.5f * (s2 - qtot) + ftot + bias[0];
    }
}

extern "C" void kernel_launch(void* const* d_in, const int* in_sizes, int n_in,
                              void* d_out, int out_size, void* d_ws, size_t ws_size,
                              hipStream_t stream) {
    const int*   Xi   = (const int*)  d_in[0];
    const float* Xv   = (const float*)d_in[1];
    const float* emb1 = (const float*)d_in[2];
    const float* emb2 = (const float*)d_in[3];
    const float* W1   = (const float*)d_in[4];
    const float* b1   = (const float*)d_in[5];
    const float* W2   = (const float*)d_in[6];
    const float* b2   = (const float*)d_in[7];
    const float* bias = (const float*)d_in[8];
    float* out = (float*)d_out;
    __bf16* ws = (__bf16*)d_ws;

    swizzle_w1_kernel<<<(KSTEPS*2*64 + 255)/256, 256, 0, stream>>>(W1, ws);
    deepfm_main<<<BATCH/16, 256, 0, stream>>>(Xi, Xv, emb1, emb2, ws, b1, W2, b2, bias, out);
}

// Round 5
// 36.046 us; speedup vs baseline: 1.0845x; 1.0845x over previous
//
#include <hip/hip_runtime.h>
#include <hip/hip_bf16.h>

#define F_FIELDS 39
#define VOCAB    100000
#define EMB      16
#define BATCH    16384
#define H1       32
#define H2       32
#define KSTEPS   20   /* K = 640 = 20 x 32 */
#define KPW      5    /* MFMA k-steps per wave (4-way K-split) */
#define FRAG_OFF (640*1024)   /* float offset of W1-frag region in d_ws (ws1 needs 638976) */

typedef __bf16 bf16x8 __attribute__((ext_vector_type(8)));
typedef float  f32x4  __attribute__((ext_vector_type(4)));

// ---------------- pre-kernel: first-order products (field-clustered) + W1 swizzle ----------------
// Grid 39*32: block = (field, chunk-of-512-samples). Consecutive blockIdx share a field, so the
// chip sweeps emb1 field-by-field in time: per-field slice = 400 KB -> L2-resident, ~5x line reuse.
// ws1[b*39+f] = emb1[f, Xi[b,f]] * Xv[b,f]   (deterministic, every slot written)
__global__ __launch_bounds__(256) void prep_kernel(
    const int*   __restrict__ Xi,  const float* __restrict__ Xv,
    const float* __restrict__ emb1,const float* __restrict__ W1,
    float* __restrict__ ws1, __bf16* __restrict__ wsfrag)
{
    const int blk = blockIdx.x;
    const int fld   = blk >> 5;     // 0..38
    const int chunk = blk & 31;
    const int t = threadIdx.x;
    const int b0 = chunk * 512 + t * 2;
    #pragma unroll
    for (int j = 0; j < 2; ++j) {
        int b = b0 + j;
        int idx  = Xi[b * F_FIELDS + fld];
        float xv = Xv[b * F_FIELDS + fld];
        ws1[b * F_FIELDS + fld] = emb1[fld * VOCAB + idx] * xv;
    }
    // W1 (f32 [624][32]) -> bf16 MFMA-B fragments, folded into first 10 blocks.
    // frag id = (kstep*2+nhalf)*64+lane; elem j: k = kstep*32+(lane>>4)*8+j, n = nhalf*16+(lane&15)
    if (blk < 10) {
        int fidx = blk * 256 + t;
        if (fidx < KSTEPS * 2 * 64) {
            int lane = fidx & 63;
            int nh   = (fidx >> 6) & 1;
            int ks   = fidx >> 7;
            int k0   = ks * 32 + (lane >> 4) * 8;
            int n    = nh * 16 + (lane & 15);
            __bf16 vals[8];
            #pragma unroll
            for (int j = 0; j < 8; ++j) {
                int k = k0 + j;
                vals[j] = (k < F_FIELDS * EMB) ? (__bf16)W1[k * H1 + n] : (__bf16)0.0f;
            }
            *reinterpret_cast<bf16x8*>(&wsfrag[fidx * 8]) = *reinterpret_cast<const bf16x8*>(vals);
        }
    }
}

// ---------------- main kernel (R3 structure, emb1 path removed) ----------------
// Block = 256 threads = 4 waves = 16 samples; K split 4-way by wave.
// Wave h owns ksteps = 4*ks'+h... lane map: sample = lane&15; q = lane>>4; fpar = q>>1; eoff = (q&1)*8.
//   field f = 8*ks' + 2*h + fpar  (f == 39 masked via xv=0)
// A-frag: row = lane&15, k_local = q*8+j.   C-frag: row = q*4+reg, col = lane&15.
__global__ __launch_bounds__(256, 4) void deepfm_main(
    const int*   __restrict__ Xi,  const float* __restrict__ Xv,
    const float* __restrict__ emb2,
    const __bf16* __restrict__ wsW1, const float* __restrict__ ws1,
    const float* __restrict__ b1,  const float* __restrict__ W2,
    const float* __restrict__ b2,  const float* __restrict__ bias,
    float* __restrict__ out)
{
    __shared__ int   sXi[16 * F_FIELDS];   // 2.4 KB
    __shared__ float sXv[16 * F_FIELDS];   // 2.4 KB
    __shared__ float pacc[4][16][32];      // 8 KB   per-wave layer-1 partials
    __shared__ float sbuf[4][16][16];      // 4 KB   per-wave FM s-vector partials
    __shared__ float qbuf[4][16];          // per-wave FM sq-sum partials
    __shared__ float W2s[H1 * H2];         // 4 KB
    __shared__ float hs[16][32];           // 2 KB   relu(layer-1)

    const int t    = threadIdx.x;
    const int h    = t >> 6;
    const int l    = t & 63;
    const int sloc = l & 15;
    const int q    = l >> 4;
    const int fpar = q >> 1;
    const int eoff = (q & 1) * 8;
    const int blk  = blockIdx.x;

    // coalesced stage of this block's Xi/Xv rows
    {
        const int base = blk * 16 * F_FIELDS;
        for (int i = t; i < 16 * F_FIELDS; i += 256) {
            sXi[i] = Xi[base + i];
            sXv[i] = Xv[base + i];
        }
    }
    reinterpret_cast<float4*>(W2s)[t] = reinterpret_cast<const float4*>(W2)[t];
    __syncthreads();

    // ---- gather issue: 10 float4 loads per lane (plain cached loads) ----
    float xvm[KPW];
    float4 g0[KPW], g1[KPW];
    #pragma unroll
    for (int ks = 0; ks < KPW; ++ks) {
        int f = 8 * ks + 2 * h + fpar;
        bool v = (f < F_FIELDS);
        int fi = v ? f : 0;
        int idx = sXi[sloc * F_FIELDS + fi];
        xvm[ks] = v ? sXv[sloc * F_FIELDS + fi] : 0.0f;
        const float4* rp = reinterpret_cast<const float4*>(emb2 + (fi * VOCAB + idx) * EMB + eoff);
        g0[ks] = rp[0];
        g1[ks] = rp[1];
    }

    // ---- consume: FM stats + layer-1 MFMA (B-frags from L2) ----
    const bf16x8* wsf = reinterpret_cast<const bf16x8*>(wsW1);
    f32x4 acc0 = {0.f,0.f,0.f,0.f}, acc1 = {0.f,0.f,0.f,0.f};
    float sa[8];
    float qq = 0.f;
    #pragma unroll
    for (int j = 0; j < 8; ++j) sa[j] = 0.f;

    #pragma unroll
    for (int ks = 0; ks < KPW; ++ks) {
        int kstep = 4 * ks + h;
        bf16x8 fr0 = wsf[(kstep * 2 + 0) * 64 + l];
        bf16x8 fr1 = wsf[(kstep * 2 + 1) * 64 + l];
        float xv = xvm[ks];
        float e[8] = { g0[ks].x*xv, g0[ks].y*xv, g0[ks].z*xv, g0[ks].w*xv,
                       g1[ks].x*xv, g1[ks].y*xv, g1[ks].z*xv, g1[ks].w*xv };
        bf16x8 a;
        #pragma unroll
        for (int j = 0; j < 8; ++j) {
            a[j] = (__bf16)e[j];
            sa[j] += e[j];
            qq   += e[j]*e[j];
        }
        acc0 = __builtin_amdgcn_mfma_f32_16x16x32_bf16(a, fr0, acc0, 0, 0, 0);
        acc1 = __builtin_amdgcn_mfma_f32_16x16x32_bf16(a, fr1, acc1, 0, 0, 0);
    }

    // ---- FM partial reduce within wave (combine field parity: lane^32, same eoff) ----
    float sf[8];
    #pragma unroll
    for (int j = 0; j < 8; ++j) sf[j] = sa[j] + __shfl_xor(sa[j], 32);
    qq += __shfl_xor(qq, 32);
    qq += __shfl_xor(qq, 16);
    if (q < 2) {   // q=0 -> positions 0..7, q=1 -> positions 8..15
        float4* srow = reinterpret_cast<float4*>(&sbuf[h][sloc][q * 8]);
        srow[0] = make_float4(sf[0], sf[1], sf[2], sf[3]);
        srow[1] = make_float4(sf[4], sf[5], sf[6], sf[7]);
    }
    if (l < 16) qbuf[h][sloc] = qq;

    // ---- layer-1 partials -> LDS (b1 folded into wave 0) ----
    float badd0 = (h == 0) ? b1[sloc]      : 0.f;
    float badd1 = (h == 0) ? b1[16 + sloc] : 0.f;
    #pragma unroll
    for (int r = 0; r < 4; ++r) {
        int row = q * 4 + r;
        pacc[h][row][sloc]      = acc0[r] + badd0;
        pacc[h][row][16 + sloc] = acc1[r] + badd1;
    }
    __syncthreads();

    // ---- h = relu(sum of partials) ----
    {
        int ss = t >> 4, c = t & 15;
        hs[ss][c]      = fmaxf(pacc[0][ss][c]      + pacc[1][ss][c]      + pacc[2][ss][c]      + pacc[3][ss][c],      0.f);
        hs[ss][c + 16] = fmaxf(pacc[0][ss][c + 16] + pacc[1][ss][c + 16] + pacc[2][ss][c + 16] + pacc[3][ss][c + 16], 0.f);
    }
    __syncthreads();

    // ---- final: 16 threads per sample ----
    const int so = t >> 4;
    const int u  = t & 15;

    float sv = sbuf[0][so][u] + sbuf[1][so][u] + sbuf[2][so][u] + sbuf[3][so][u];
    float s2 = sv * sv;

    // first-order from ws1 (L2-resident, 39 contiguous floats/sample), ride the psum reduce
    const float* w1row = ws1 + (blk * 16 + so) * F_FIELDS;
    float fo = w1row[u] + w1row[16 + u];
    if (u < 7) fo += w1row[32 + u];

    float a0 = b2[2 * u], a1 = b2[2 * u + 1];
    #pragma unroll
    for (int i = 0; i < H1; ++i) {
        float hv = hs[so][i];
        a0 += hv * W2s[i * H2 + 2 * u];
        a1 += hv * W2s[i * H2 + 2 * u + 1];
    }
    float psum = fmaxf(a0, 0.f) + fmaxf(a1, 0.f) + fo;

    psum += __shfl_xor(psum, 1);  s2 += __shfl_xor(s2, 1);
    psum += __shfl_xor(psum, 2);  s2 += __shfl_xor(s2, 2);
    psum += __shfl_xor(psum, 4);  s2 += __shfl_xor(s2, 4);
    psum += __shfl_xor(psum, 8);  s2 += __shfl_xor(s2, 8);

    if (u == 0) {
        float qtot = qbuf[0][so] + qbuf[1][so] + qbuf[2][so] + qbuf[3][so];
        out[blk * 16 + so] = psum + 0.5f * (s2 - qtot) + bias[0];
    }
}

extern "C" void kernel_launch(void* const* d_in, const int* in_sizes, int n_in,
                              void* d_out, int out_size, void* d_ws, size_t ws_size,
                              hipStream_t stream) {
    const int*   Xi   = (const int*)  d_in[0];
    const float* Xv   = (const float*)d_in[1];
    const float* emb1 = (const float*)d_in[2];
    const float* emb2 = (const float*)d_in[3];
    const float* W1   = (const float*)d_in[4];
    const float* b1   = (const float*)d_in[5];
    const float* W2   = (const float*)d_in[6];
    const float* b2   = (const float*)d_in[7];
    const float* bias = (const float*)d_in[8];
    float* out = (float*)d_out;

    float*  ws1    = (float*)d_ws;                       // [16384*39] first-order products
    __bf16* wsfrag = (__bf16*)((float*)d_ws + FRAG_OFF); // 40 KB W1 fragments

    prep_kernel<<<F_FIELDS * 32, 256, 0, stream>>>(Xi, Xv, emb1, W1, ws1, wsfrag);
    deepfm_main<<<BATCH/16, 256, 0, stream>>>(Xi, Xv, emb2, wsfrag, ws1, b1, W2, b2, bias, out);
}